// Round 3
// baseline (809.635 us; speedup 1.0000x reference)
//
#include <hip/hip_runtime.h>

// Problem constants
#define NFR   128      // N frames
#define PP    576      // patches
#define DD    1536     // dim
#define LMM   4096
#define NQQ   64
#define PQ    9        // P / NQ
#define NCUBES 8
#define NSEL  9        // 1 forced + 8 cubes
#define D4    384      // DD / 4 (float4 columns)

// ---------------- ws layout (float offsets), total ~13.4 MB ----------------
// Region A (0 .. 1,572,864) is time-shared: part -> Cpart(DxD,8 splits) -> Cpart(thumb,4 splits)
#define OFF_A      0u
#define OFF_VFMEAN 1572864u      // [128][1536]
#define OFF_MOM    1769472u      // [128][1536]  momMean (row 127 zeroed)
#define OFF_XN     1966080u      // [128][1536]
#define OFF_H      2162688u      // [128][1536]
#define OFF_PPART  2359296u      // [9][64][1536] pooled partials
#define OFF_POOLED 3244032u      // [64][1536]
#define OFF_Y      3342336u      // [127]
#define OFF_SEL    3342464u      // [9] ints

// Output layout (fp32): gate_logits [127,2] @0, thumbnail [64,4096] @254, z_hard [128] @262398
#define OUT_GATE  0
#define OUT_THUMB 254
#define OUT_Z     262398

// ---------------- K1: per-frame patch-sum partials ----------------
// grid (128 frames, 8 p-chunks), 384 threads; each thread one float4 column.
__global__ __launch_bounds__(384) void k1_partial(const float* __restrict__ vf,
                                                  float* __restrict__ part) {
    const int n  = blockIdx.x;
    const int ps = blockIdx.y;
    const int c4 = threadIdx.x;
    const float4* v = (const float4*)vf;
    float4 acc = make_float4(0.f, 0.f, 0.f, 0.f);
    int base = (n * PP + ps * 72) * D4 + c4;
#pragma unroll 8
    for (int p = 0; p < 72; ++p) {
        float4 x = v[base + p * D4];
        acc.x += x.x; acc.y += x.y; acc.z += x.z; acc.w += x.w;
    }
    ((float4*)part)[(n * 8 + ps) * D4 + c4] = acc;
}

// ---------------- K2a: combine partials -> vfMean ----------------
__global__ __launch_bounds__(256) void k2a_mean(const float* __restrict__ part,
                                                float* __restrict__ vfMean) {
    const int n = blockIdx.x;
    const int d = blockIdx.y * 256 + threadIdx.x;
    float s = 0.f;
#pragma unroll
    for (int ps = 0; ps < 8; ++ps) s += part[(n * 8 + ps) * DD + d];
    vfMean[n * DD + d] = s * (1.0f / 576.0f);
}

// ---------------- K2b: EMA scan over frame diffs -> momMean ----------------
__global__ __launch_bounds__(256) void k2b_scan(const float* __restrict__ vfMean,
                                                float* __restrict__ momMean) {
    const int d = blockIdx.x * 256 + threadIdx.x;
    float prev = vfMean[d];
    float cur  = vfMean[DD + d];
    float ema  = cur - prev;        // delta_1 = d_1
    momMean[d] = ema;
    prev = cur;
    for (int n = 2; n < NFR; ++n) {
        cur = vfMean[n * DD + d];
        float diff = cur - prev;
        ema = 0.5f * diff + 0.5f * ema;   // ALPHA = 0.5
        momMean[(n - 1) * DD + d] = ema;
        prev = cur;
    }
    momMean[127 * DD + d] = 0.f;    // pad row for M=128 GEMM
}

// ---------------- split-K fp32 GEMM: Cpart[s] = A[:,ks] @ B[ks,:] ----------------
// Deterministic (no atomics). grid (N/64, M/64, splits), 256 threads.
#define GKC 16
__global__ __launch_bounds__(256) void gemm_sk(const float* __restrict__ A,
                                               const float* __restrict__ B,
                                               float* __restrict__ Cpart,
                                               int M, int N, int K, int kChunk) {
    const int j0 = blockIdx.x * 64;
    const int i0 = blockIdx.y * 64;
    const int s  = blockIdx.z;
    const int k0 = s * kChunk;
    __shared__ float As[GKC][68];   // [k][i], padded
    __shared__ float Bs[GKC][68];   // [k][j], padded
    const int tid = threadIdx.x;
    const int tx = tid & 15, ty = tid >> 4;
    const int ai = tid >> 2, ak4 = (tid & 3) * 4;   // A: row ai, k-offset ak4
    const int bk = tid >> 4, bj4 = (tid & 15) * 4;  // B: k-row bk, j-offset bj4
    float c[4][4] = {};
    for (int kk = k0; kk < k0 + kChunk; kk += GKC) {
        float4 av = *(const float4*)(A + (size_t)(i0 + ai) * K + kk + ak4);
        float4 bv = *(const float4*)(B + (size_t)(kk + bk) * N + j0 + bj4);
        __syncthreads();
        As[ak4 + 0][ai] = av.x; As[ak4 + 1][ai] = av.y;
        As[ak4 + 2][ai] = av.z; As[ak4 + 3][ai] = av.w;
        Bs[bk][bj4 + 0] = bv.x; Bs[bk][bj4 + 1] = bv.y;
        Bs[bk][bj4 + 2] = bv.z; Bs[bk][bj4 + 3] = bv.w;
        __syncthreads();
#pragma unroll
        for (int k = 0; k < GKC; ++k) {
            float a0 = As[k][ty * 4 + 0], a1 = As[k][ty * 4 + 1];
            float a2 = As[k][ty * 4 + 2], a3 = As[k][ty * 4 + 3];
            float b0 = Bs[k][tx * 4 + 0], b1 = Bs[k][tx * 4 + 1];
            float b2 = Bs[k][tx * 4 + 2], b3 = Bs[k][tx * 4 + 3];
            c[0][0] += a0 * b0; c[0][1] += a0 * b1; c[0][2] += a0 * b2; c[0][3] += a0 * b3;
            c[1][0] += a1 * b0; c[1][1] += a1 * b1; c[1][2] += a1 * b2; c[1][3] += a1 * b3;
            c[2][0] += a2 * b0; c[2][1] += a2 * b1; c[2][2] += a2 * b2; c[2][3] += a2 * b3;
            c[3][0] += a3 * b0; c[3][1] += a3 * b1; c[3][2] += a3 * b2; c[3][3] += a3 * b3;
        }
    }
    float* Cp = Cpart + (size_t)s * M * N;
#pragma unroll
    for (int ii = 0; ii < 4; ++ii)
#pragma unroll
        for (int jj = 0; jj < 4; ++jj)
            Cp[(size_t)(i0 + ty * 4 + ii) * N + j0 + tx * 4 + jj] = c[ii][jj];
}

// ---------------- block reduce (blockDim = 256) ----------------
__device__ __forceinline__ float blockSum(float v, float* sb) {
#pragma unroll
    for (int o = 32; o > 0; o >>= 1) v += __shfl_down(v, o);
    __syncthreads();
    if ((threadIdx.x & 63) == 0) sb[threadIdx.x >> 6] = v;
    __syncthreads();
    return sb[0] + sb[1] + sb[2] + sb[3];
}

// ---------------- K4: reduce split-K partials + b_agg, LayerNorm -> xn ----------------
__global__ __launch_bounds__(256) void k4_ln(const float* __restrict__ Cpart,
                                             const float* __restrict__ b_agg,
                                             const float* __restrict__ ln_g,
                                             const float* __restrict__ ln_b,
                                             float* __restrict__ xn) {
    __shared__ float sb[4];
    const int n = blockIdx.x;
    if (n == 127) {   // pad row: keep defined (zeros) for the W1 GEMM
#pragma unroll
        for (int t = 0; t < 6; ++t) xn[n * DD + t * 256 + threadIdx.x] = 0.f;
        return;
    }
    float v[6];
#pragma unroll
    for (int t = 0; t < 6; ++t) {
        int d = t * 256 + threadIdx.x;
        float s = b_agg[d];
#pragma unroll
        for (int ss = 0; ss < 8; ++ss) s += Cpart[ss * (NFR * DD) + n * DD + d];
        v[t] = s;
    }
    float local = v[0] + v[1] + v[2] + v[3] + v[4] + v[5];
    float mu = blockSum(local, sb) * (1.0f / (float)DD);
    float ls = 0.f;
#pragma unroll
    for (int t = 0; t < 6; ++t) { float dd = v[t] - mu; ls += dd * dd; }
    float var = blockSum(ls, sb) * (1.0f / (float)DD);
    float rstd = rsqrtf(var + 1e-5f);
#pragma unroll
    for (int t = 0; t < 6; ++t) {
        int d = t * 256 + threadIdx.x;
        xn[n * DD + d] = (v[t] - mu) * rstd * ln_g[d] + ln_b[d];
    }
}

// ---------------- K5b: reduce partials + b1, exact GELU -> h ----------------
__global__ __launch_bounds__(256) void k5b_gelu(const float* __restrict__ Cpart,
                                                const float* __restrict__ b1,
                                                float* __restrict__ h) {
    const int n = blockIdx.x;
    const int d = blockIdx.y * 256 + threadIdx.x;
    float s = b1[d];
#pragma unroll
    for (int ss = 0; ss < 8; ++ss) s += Cpart[ss * (NFR * DD) + n * DD + d];
    h[n * DD + d] = 0.5f * s * (1.0f + erff(s * 0.70710678118654752f));
}

// ---------------- K6: gate logits (h @ W2 + b2), gumbel-softmax y ----------------
__global__ __launch_bounds__(256) void k6_gate(const float* __restrict__ h,
                                               const float* __restrict__ W2,
                                               const float* __restrict__ b2,
                                               const float* __restrict__ u,
                                               float* __restrict__ outGate,
                                               float* __restrict__ y) {
    __shared__ float sb[4];
    const int n = blockIdx.x;
    float a0 = 0.f, a1 = 0.f;
#pragma unroll
    for (int t = 0; t < 6; ++t) {
        int d = t * 256 + threadIdx.x;
        float hv = h[n * DD + d];
        a0 += hv * W2[2 * d];
        a1 += hv * W2[2 * d + 1];
    }
    a0 = blockSum(a0, sb);
    a1 = blockSum(a1, sb);
    if (threadIdx.x == 0) {
        float gl0 = a0 + b2[0], gl1 = a1 + b2[1];
        outGate[2 * n]     = gl0;
        outGate[2 * n + 1] = gl1;
        float g0 = -logf(-logf(u[2 * n]     + 1e-20f) + 1e-20f);
        float g1 = -logf(-logf(u[2 * n + 1] + 1e-20f) + 1e-20f);
        float s0 = (gl0 + g0 * 0.1f) * 2.0f;   // /TEMP, TEMP=0.5
        float s1 = (gl1 + g1 * 0.1f) * 2.0f;
        float m = fmaxf(s0, s1);
        float e0 = expf(s0 - m), e1 = expf(s1 - m);
        y[n] = e1 / (e0 + e1);
    }
}

// ---------------- K7: top-8 selection, z_hard output ----------------
__global__ __launch_bounds__(64) void k7_topk(const float* __restrict__ y,
                                              int* __restrict__ selFrames,
                                              float* __restrict__ outZ) {
    __shared__ float yv[127];
    __shared__ int   tk[127];
    const int t = threadIdx.x;
    for (int i = t; i < 127; i += 64) { yv[i] = y[i]; tk[i] = 0; }
    __syncthreads();
    if (t == 0) {
        selFrames[0] = 0;  // forced first keyframe
        for (int c = 0; c < NCUBES; ++c) {
            float best = -1e30f; int bi = 0;
            for (int i = 0; i < 127; ++i)
                if (!tk[i] && yv[i] > best) { best = yv[i]; bi = i; }  // ties -> lowest idx (lax.top_k)
            tk[bi] = 1;
            selFrames[c + 1] = bi + 1;
        }
        outZ[0] = 1.0f;
        // forward value of straight-through z is exactly y_hard in fp32:
        // (1-y)+y == 1 (Sterbenz), (0-y)+y == 0
        for (int i = 0; i < 127; ++i)
            outZ[1 + i] = tk[i] ? 1.0f : 0.0f;
    }
}

// ---------------- K8: selected-frame pooled partials ----------------
__global__ __launch_bounds__(384) void k8_pool(const float* __restrict__ vf,
                                               const int* __restrict__ selFrames,
                                               float* __restrict__ pPart) {
    const int q = blockIdx.x, slot = blockIdx.y, c4 = threadIdx.x;
    const int n = selFrames[slot];
    const float4* v = (const float4*)vf;
    float4 acc = make_float4(0.f, 0.f, 0.f, 0.f);
    int base = (n * PP + q * PQ) * D4 + c4;
#pragma unroll
    for (int r = 0; r < PQ; ++r) {
        float4 x = v[base + r * D4];
        acc.x += x.x; acc.y += x.y; acc.z += x.z; acc.w += x.w;
    }
    ((float4*)pPart)[(slot * NQQ + q) * D4 + c4] = acc;
}

// ---------------- K8b: reduce pooled partials (x 1/81) ----------------
__global__ __launch_bounds__(256) void k8b_pool(const float* __restrict__ pPart,
                                                float* __restrict__ pooled) {
    const int q = blockIdx.x;
    const int d = blockIdx.y * 256 + threadIdx.x;
    float s = 0.f;
#pragma unroll
    for (int slot = 0; slot < NSEL; ++slot) s += pPart[(slot * NQQ + q) * DD + d];
    pooled[q * DD + d] = s * (1.0f / 81.0f);   // / z.sum()=9 and / 9 patches
}

// ---------------- K10: reduce thumbnail partials (4 splits) + b_th ----------------
__global__ __launch_bounds__(256) void k10_thumb(const float* __restrict__ Cpart,
                                                 const float* __restrict__ b_th,
                                                 float* __restrict__ outT) {
    const int q = blockIdx.x;
    const int l = blockIdx.y * 256 + threadIdx.x;
    float s = b_th[l];
#pragma unroll
    for (int ss = 0; ss < 4; ++ss) s += Cpart[ss * (NQQ * LMM) + q * LMM + l];
    outT[q * LMM + l] = s;
}

extern "C" void kernel_launch(void* const* d_in, const int* in_sizes, int n_in,
                              void* d_out, int out_size, void* d_ws, size_t ws_size,
                              hipStream_t stream) {
    // Inputs are fp32 (reference dtypes); output fp32.
    const float* vf    = (const float*)d_in[0];
    const float* u     = (const float*)d_in[1];
    const float* W_agg = (const float*)d_in[2];
    const float* b_agg = (const float*)d_in[3];
    const float* ln_g  = (const float*)d_in[4];
    const float* ln_b  = (const float*)d_in[5];
    const float* W1    = (const float*)d_in[6];
    const float* b1    = (const float*)d_in[7];
    const float* W2    = (const float*)d_in[8];
    const float* b2    = (const float*)d_in[9];
    const float* W_th  = (const float*)d_in[10];
    const float* b_th  = (const float*)d_in[11];

    float* ws = (float*)d_ws;
    float* regA    = ws + OFF_A;       // part, later Cpart
    float* vfMean  = ws + OFF_VFMEAN;
    float* momMean = ws + OFF_MOM;
    float* xn      = ws + OFF_XN;
    float* h       = ws + OFF_H;
    float* pPart   = ws + OFF_PPART;
    float* pooled  = ws + OFF_POOLED;
    float* yv      = ws + OFF_Y;
    int*   sel     = (int*)(ws + OFF_SEL);

    float* out = (float*)d_out;
    float* outGate  = out + OUT_GATE;
    float* outThumb = out + OUT_THUMB;
    float* outZ     = out + OUT_Z;

    // Step 1+2 collapsed: patch-means, EMA scan on means, small GEMM
    k1_partial<<<dim3(NFR, 8), 384, 0, stream>>>(vf, regA);
    k2a_mean<<<dim3(NFR, 6), 256, 0, stream>>>(regA, vfMean);
    k2b_scan<<<6, 256, 0, stream>>>(vfMean, momMean);
    // feat_raw = momMean @ W_agg (8-way split-K partials into regA)
    gemm_sk<<<dim3(24, 2, 8), 256, 0, stream>>>(momMean, W_agg, regA, NFR, DD, DD, 192);
    k4_ln<<<NFR, 256, 0, stream>>>(regA, b_agg, ln_g, ln_b, xn);
    // h_raw = xn @ W1
    gemm_sk<<<dim3(24, 2, 8), 256, 0, stream>>>(xn, W1, regA, NFR, DD, DD, 192);
    k5b_gelu<<<dim3(127, 6), 256, 0, stream>>>(regA, b1, h);
    k6_gate<<<127, 256, 0, stream>>>(h, W2, b2, u, outGate, yv);
    k7_topk<<<1, 64, 0, stream>>>(yv, sel, outZ);
    k8_pool<<<dim3(NQQ, NSEL), 384, 0, stream>>>(vf, sel, pPart);
    k8b_pool<<<dim3(NQQ, 6), 256, 0, stream>>>(pPart, pooled);
    // thumb_raw = pooled @ W_th (4-way split-K into regA)
    gemm_sk<<<dim3(64, 1, 4), 256, 0, stream>>>(pooled, W_th, regA, NQQ, LMM, DD, 384);
    k10_thumb<<<dim3(NQQ, 16), 256, 0, stream>>>(regA, b_th, outThumb);
}